// Round 11
// baseline (157.573 us; speedup 1.0000x reference)
//
#include <hip/hip_runtime.h>
#include <math.h>

#define NB 256     // batch
#define IC 1152    // input capsules
#define OC 10      // output capsules
#define OU 16      // output units
#define IK 8       // input units
#define KTOT (IC * IK)        // 9216
#define NTOT (OC * OU)        // 160
#define S_KS 16               // s-pass K-splits (576 k = 18 MFMA each)

typedef __attribute__((ext_vector_type(8))) short short8;
typedef __attribute__((ext_vector_type(4))) float f32x4;

static __device__ __forceinline__ unsigned short f2bf(float f) {
    unsigned u = __float_as_uint(f);
    unsigned r = (u + 0x7FFF + ((u >> 16) & 1)) >> 16;   // RNE
    return (unsigned short)r;
}

// ---- prep: zero blog + inp -> bf16 [256][9216] AND bf16 transpose [9216][256]
__global__ __launch_bounds__(256) void prep_kernel(
    const float* __restrict__ inp,
    float* __restrict__ blog,
    unsigned short* __restrict__ inpb,   // [256][9216]
    unsigned short* __restrict__ inpT)   // [9216][256]
{
    const int kt  = blockIdx.x;      // 0..143
    const int bt  = blockIdx.y;      // 0..3
    const int tid = threadIdx.x;

    {
        int bid = blockIdx.y * 144 + blockIdx.x;
        if (bid < 45) blog[bid * 256 + tid] = 0.f;
    }

    __shared__ unsigned short sh[64][65];

#pragma unroll
    for (int j = 0; j < 4; ++j) {
        int q     = j * 256 + tid;
        int b_loc = q >> 4;
        int kq    = (q & 15) * 4;
        float4 g = *(const float4*)&inp[(size_t)(bt * 64 + b_loc) * KTOT + kt * 64 + kq];
        unsigned short h0 = f2bf(g.x), h1 = f2bf(g.y), h2 = f2bf(g.z), h3 = f2bf(g.w);
        sh[kq][b_loc] = h0; sh[kq + 1][b_loc] = h1;
        sh[kq + 2][b_loc] = h2; sh[kq + 3][b_loc] = h3;
        short4 pk = { (short)h0, (short)h1, (short)h2, (short)h3 };
        *(short4*)&inpb[(size_t)(bt * 64 + b_loc) * KTOT + kt * 64 + kq] = pk;
    }
    __syncthreads();

#pragma unroll
    for (int j = 0; j < 4; ++j) {
        int q     = j * 256 + tid;
        int k_loc = q >> 4;
        int b4    = (q & 15) * 4;
        short4 pk = { (short)sh[k_loc][b4],     (short)sh[k_loc][b4 + 1],
                      (short)sh[k_loc][b4 + 2], (short)sh[k_loc][b4 + 3] };
        *(short4*)&inpT[(size_t)(kt * 64 + k_loc) * 256 + bt * 64 + b4] = pk;
    }
}

// ---- s-pass via MFMA, softmax+Wc fused in-block -------------------------
#define BLP 584   // B-tile row pitch in shorts (576 + 8 pad)
__global__ __launch_bounds__(256) void spass_kernel(
    const unsigned short* __restrict__ inpb,  // [256][9216]
    const float* __restrict__ W,              // [1152][10][16][8]
    const float* __restrict__ blog,           // [1152][10]
    float* __restrict__ part)                 // [16][256][160]
{
    const int bid  = blockIdx.x;
    const int nt   = bid % 10;           // output capsule o
    const int ks   = (bid / 10) % 16;    // k-split
    const int mtg  = bid / 160;          // 0..3
    const int tid  = threadIdx.x;
    const int w    = tid >> 6;           // wave 0..3
    const int lane = tid & 63;
    const int l15  = lane & 15;
    const int koff = (lane >> 4) * 8;
    const int k0   = ks * 576;
    const int i0   = ks * 72;
    const int mt   = mtg * 4 + w;

    __shared__ unsigned short Bl[16 * BLP];   // 18.7 KB
    __shared__ float c_loc[72];

    if (tid < 72) {
        const float* br = &blog[(size_t)(i0 + tid) * OC];
        float x[OC], m = -1e30f;
#pragma unroll
        for (int o = 0; o < OC; ++o) { x[o] = br[o]; m = fmaxf(m, x[o]); }
        float ssum = 0.f;
#pragma unroll
        for (int o = 0; o < OC; ++o) ssum += expf(x[o] - m);
        c_loc[tid] = expf(x[nt] - m) / ssum;
    }
    __syncthreads();

#pragma unroll
    for (int jj = 0; jj < 5; ++jj) {
        int q = jj * 256 + tid;          // (i_loc, u) pairs: 72*16 = 1152
        if (q < 1152) {
            int i_loc = q >> 4, u = q & 15;
            const float* wr = W + (((size_t)(i0 + i_loc) * OC + nt) * OU + u) * IK;
            float4 a = *(const float4*)wr;
            float4 b = *(const float4*)(wr + 4);
            float cc = c_loc[i_loc];
            union { short8 v; unsigned short us[8]; } pk;
            pk.us[0] = f2bf(cc * a.x); pk.us[1] = f2bf(cc * a.y);
            pk.us[2] = f2bf(cc * a.z); pk.us[3] = f2bf(cc * a.w);
            pk.us[4] = f2bf(cc * b.x); pk.us[5] = f2bf(cc * b.y);
            pk.us[6] = f2bf(cc * b.z); pk.us[7] = f2bf(cc * b.w);
            *(short8*)&Bl[u * BLP + i_loc * 8] = pk.v;
        }
    }
    __syncthreads();

    const unsigned short* ap  = inpb + (size_t)(mt * 16 + l15) * KTOT + k0 + koff;
    const unsigned short* bls = &Bl[l15 * BLP + koff];

    f32x4 acc = {0.f, 0.f, 0.f, 0.f};
#pragma unroll
    for (int kk = 0; kk < 18; ++kk) {
        short8 av = *(const short8*)(ap + kk * 32);
        short8 bv = *(const short8*)(bls + kk * 32);
        acc = __builtin_amdgcn_mfma_f32_16x16x32_bf16(av, bv, acc, 0, 0, 0);
    }

    float* pp = part + ((size_t)ks * NB + mt * 16 + (lane >> 4) * 4) * NTOT + nt * 16 + l15;
#pragma unroll
    for (int r = 0; r < 4; ++r)
        pp[(size_t)r * NTOT] = acc[r];
}

// ---- final reduce partials + squash -> vout ------------------------------
__global__ __launch_bounds__(256) void reduce_squash_kernel(
    const float* __restrict__ part, float* __restrict__ vout)
{
    const int tid = threadIdx.x;
    const int el  = tid & 31;
    const int kl  = tid >> 5;        // 0..7
    const int e   = blockIdx.x * 32 + el;

    float a = part[(size_t)(kl * 2) * (NB * NTOT) + e]
            + part[(size_t)(kl * 2 + 1) * (NB * NTOT) + e];

    __shared__ float red[8][36];
    red[kl][el] = a;
    __syncthreads();

    if (tid < 32) {
        float s = ((red[0][el] + red[1][el]) + (red[2][el] + red[3][el]))
                + ((red[4][el] + red[5][el]) + (red[6][el] + red[7][el]));
        float sq = s * s;
        sq += __shfl_xor(sq, 1);
        sq += __shfl_xor(sq, 2);
        sq += __shfl_xor(sq, 4);
        sq += __shfl_xor(sq, 8);
        vout[e] = s * (sq / ((1.f + sq) * sqrtf(sq + 1e-9f)));
    }
}

// ---- fused reduce+squash+delta: one block = one nt x 16 mt ---------------
// grid (36, 10), 1024 thr = 16 waves. Prologue: v-slice for o=nt into LDS.
// Main: G[ik][ou] = sum_b inpT[ik][b]*v[b][ou], fused W-contraction -> blog.
__global__ __launch_bounds__(1024) void delta_fused_kernel(
    const float* __restrict__ part,           // [16][256][160]
    const unsigned short* __restrict__ inpT,  // [9216][256]
    const float* __restrict__ W,              // [1152][10][16][8]
    float* __restrict__ blog)                 // [1152][10] accum
{
    const int mtg = blockIdx.x;      // 0..35
    const int nt  = blockIdx.y;      // 0..9 (= o)
    const int tid = threadIdx.x;

    __shared__ float sred[256][17];            // s[b][u], 17.4 KB
    __shared__ float alpha[256];
    __shared__ unsigned short vT_loc[16][264]; // v[u][b] bf16, 8.4 KB

    // reduce: s[b][u] = sum_ks part[ks][b][nt*16+u]
    {
        const int nl = tid & 15;
        const int bq = tid >> 4;     // 0..63
#pragma unroll
        for (int rep = 0; rep < 4; ++rep) {
            int b = bq + rep * 64;
            const float* pp = part + (size_t)b * NTOT + nt * 16 + nl;
            float s = 0.f;
#pragma unroll
            for (int ks = 0; ks < S_KS; ++ks)
                s += pp[(size_t)ks * (NB * NTOT)];
            sred[b][nl] = s;
        }
    }
    __syncthreads();

    if (tid < 256) {
        const int b = tid;
        float sq = 0.f;
#pragma unroll
        for (int u = 0; u < 16; ++u) { float x = sred[b][u]; sq += x * x; }
        alpha[b] = sq / ((1.f + sq) * sqrtf(sq + 1e-9f));
    }
    __syncthreads();

    {
        const int nl = tid & 15;
        const int bq = tid >> 4;
#pragma unroll
        for (int rep = 0; rep < 4; ++rep) {
            int b = bq + rep * 64;
            vT_loc[nl][b] = f2bf(sred[b][nl] * alpha[b]);
        }
    }
    __syncthreads();

    // MFMA delta: wave w -> mt = mtg*16 + w
    const int w    = tid >> 6;
    const int lane = tid & 63;
    const int mt   = mtg * 16 + w;
    const int l15  = lane & 15;
    const int quad = lane >> 4;
    const int koff = quad * 8;

    const unsigned short* ap = inpT + (size_t)(mt * 16 + l15) * 256 + koff;
    const unsigned short* bp = &vT_loc[l15][koff];

    f32x4 acc = {0.f, 0.f, 0.f, 0.f};
#pragma unroll
    for (int kk = 0; kk < 8; ++kk) {
        short8 av = *(const short8*)(ap + kk * 32);
        short8 bv = *(const short8*)(bp + kk * 32);
        acc = __builtin_amdgcn_mfma_f32_16x16x32_bf16(av, bv, acc, 0, 0, 0);
    }

    // lane holds G[m=quad*4+r][n=l15]; m -> i_loc = quad>>1, k=(quad&1)*4+r; n -> u
    const int i = mt * 2 + (quad >> 1);
    const float* wr = W + (((size_t)i * OC + nt) * OU + l15) * IK + (quad & 1) * 4;
    float4 wf = *(const float4*)wr;
    float wsum = wf.x * acc[0] + wf.y * acc[1] + wf.z * acc[2] + wf.w * acc[3];

    wsum += __shfl_xor(wsum, 16);   // combine the two quads of this i
    wsum += __shfl_xor(wsum, 1);    // reduce over u
    wsum += __shfl_xor(wsum, 2);
    wsum += __shfl_xor(wsum, 4);
    wsum += __shfl_xor(wsum, 8);

    if ((lane & 31) == 0)
        blog[(size_t)i * OC + nt] += wsum * (1.0f / NB);
}

extern "C" void kernel_launch(void* const* d_in, const int* in_sizes, int n_in,
                              void* d_out, int out_size, void* d_ws, size_t ws_size,
                              hipStream_t stream) {
    const float* inp = (const float*)d_in[0];   // [256][1152][8]
    const float* W   = (const float*)d_in[1];   // [1152][10][16][8]
    float* vout = (float*)d_out;                // [256][10][16]

    float* blog = (float*)d_ws;                              // 11,520 f
    float* part = blog + IC * OC;                            // 655,360 f
    unsigned short* inpb = (unsigned short*)(part + (size_t)S_KS * NB * NTOT);
    unsigned short* inpT = inpb + (size_t)NB * KTOT;         // 2,359,296 u16

    prep_kernel<<<dim3(144, 4), dim3(256), 0, stream>>>(inp, blog, inpb, inpT);

    // t = 0
    spass_kernel<<<dim3(640), dim3(256), 0, stream>>>(inpb, W, blog, part);
    delta_fused_kernel<<<dim3(36, 10), dim3(1024), 0, stream>>>(part, inpT, W, blog);
    // t = 1
    spass_kernel<<<dim3(640), dim3(256), 0, stream>>>(inpb, W, blog, part);
    delta_fused_kernel<<<dim3(36, 10), dim3(1024), 0, stream>>>(part, inpT, W, blog);
    // t = 2 (final: no b update needed)
    spass_kernel<<<dim3(640), dim3(256), 0, stream>>>(inpb, W, blog, part);
    reduce_squash_kernel<<<dim3(NB * NTOT / 32), dim3(256), 0, stream>>>(part, vout);
}